// Round 4
// baseline (1336.723 us; speedup 1.0000x reference)
//
#include <hip/hip_runtime.h>

// MyRNNCell via MFMA f16 on gfx950 — v5: x-projection hoisted out of the
// serial loop.
//
//   h_{t+1} = tanh(h_t @ Wh + xp_t),   xp = x @ Wx + bias  (precomputed)
//
// Phase 1 (xproj_kernel, all 256 CUs): xp[b][t][u] = TANH_K*(x@Wx + bias),
// written into `out` itself (same [b][t][u] layout). HBM-bound, ~70us.
// Phase 2 (rnn_mfma_kernel, 16 WGs): the recurrence with K = 256 (h only,
// 8 slices of 32). acc initializes from xp, loaded from out[b][t][u] two
// steps ahead; each location is read exactly once (2+ barriers before the
// h-store to it — __syncthreads drains vmcnt(0), so read-before-write is
// guaranteed) and then overwritten with h. Tail prefetches (t+2 clamped
// to T-1) race benignly with h[T-1] stores; values never consumed.
//
// vs v4 (826us): serial step loses 8 of 24 MFMAs, 4 of 12 ds_read_b128,
// the x-publish and x-prefetch. New per-step pipe floors on the 16 active
// CUs: LDS ~770cy, MFMA ~620cy, VALU ~650cy (was LDS ~1150).
//
// Phase-2 structure (from v3/v4): 16 WGs x 16 batches; 512 threads =
// 8 waves (2/SIMD); wave w owns units [32w,32w+32) = 2 N-tiles.
// Double-buffered LDS h-panel, one __syncthreads per step, t-unroll x2,
// W/bias pre-scaled by 2*log2(e) (tanh = 1 - 2*rcp(exp2(acc)+1)),
// s_setprio(1) around the MFMA cluster.
//
// fp16 (not bf16): 2^-11 quantization keeps recurrent error ~1e-3 << 2e-2.

typedef _Float16 half8 __attribute__((ext_vector_type(8)));
typedef float floatx4 __attribute__((ext_vector_type(4)));

constexpr int B = 256, T = 1024, D = 128, U = 256;
constexpr int NSL = U / 32;            // 8 K-slices (h only)
constexpr int QS  = 16 * 16 + 16;      // 272 B quad stride (+16 pad: bank spread)
constexpr int SS  = 4 * QS;            // 1088 B slice stride
constexpr int BUF = NSL * SS;          // 8704 B per h-panel buffer

// 2*log2(e): pre-activation is pre-scaled so tanh needs no multiply.
constexpr float TANH_K = 2.8853900817779268f;

__device__ __forceinline__ float fexp2(float v) {
#if __has_builtin(__builtin_amdgcn_exp2f)
    return __builtin_amdgcn_exp2f(v);
#else
    return exp2f(v);
#endif
}
__device__ __forceinline__ float frcp(float v) {
#if __has_builtin(__builtin_amdgcn_rcpf)
    return __builtin_amdgcn_rcpf(v);
#else
    return 1.0f / v;
#endif
}
// a = 2*log2(e)*v  ->  tanh(v) = 1 - 2/(2^a + 1).  exp2->inf, rcp(inf)=0
// make saturation exact at both ends without clamping.
__device__ __forceinline__ float tanh_prescaled(float a) {
    float e = fexp2(a);
    return 1.0f - 2.0f * frcp(e + 1.0f);
}

__device__ __forceinline__ void cvt_write8(void* dst, float4 lo, float4 hi) {
    half8 h;
    h[0] = (_Float16)lo.x; h[1] = (_Float16)lo.y;
    h[2] = (_Float16)lo.z; h[3] = (_Float16)lo.w;
    h[4] = (_Float16)hi.x; h[5] = (_Float16)hi.y;
    h[6] = (_Float16)hi.z; h[7] = (_Float16)hi.w;
    *reinterpret_cast<half8*>(dst) = h;
}

// ---------------- Phase 1: xp = TANH_K*(x @ Wx + bias) -> out ----------------
// Rows = flattened (b,t) index; 64 rows/WG; 4 waves, wave w owns cols
// [64w, 64w+64). A-frags straight from global (one-shot stream of x).
__global__ __launch_bounds__(256, 2)
void xproj_kernel(const float* __restrict__ x, const float* __restrict__ W,
                  const float* __restrict__ bias, float* __restrict__ out)
{
    const int tid  = threadIdx.x;
    const int lane = tid & 63;
    const int wv   = tid >> 6;
    const int l15  = lane & 15;
    const int quad = lane >> 4;
    const size_t r0 = (size_t)blockIdx.x * 64;

    half8 wf[4][4];
    float bv[4];
#pragma unroll
    for (int nt = 0; nt < 4; ++nt) {
        const int n = 64 * wv + 16 * nt + l15;
        bv[nt] = bias[n] * TANH_K;
#pragma unroll
        for (int s = 0; s < 4; ++s) {
            half8 f;
#pragma unroll
            for (int j = 0; j < 8; ++j) {
                const int d = 32 * s + 8 * quad + j;      // k index into Wx
                f[j] = (_Float16)(W[(size_t)(U + d) * U + n] * TANH_K);
            }
            wf[nt][s] = f;
        }
    }

#pragma unroll
    for (int rt = 0; rt < 4; ++rt) {
        const size_t row = r0 + 16 * rt + l15;            // A row (m = l15)
        const float* xr = x + row * D + 8 * quad;
        half8 a[4];
#pragma unroll
        for (int s = 0; s < 4; ++s) {
            float4 lo = *reinterpret_cast<const float4*>(xr + 32 * s);
            float4 hi = *reinterpret_cast<const float4*>(xr + 32 * s + 4);
            half8 f;
            f[0] = (_Float16)lo.x; f[1] = (_Float16)lo.y;
            f[2] = (_Float16)lo.z; f[3] = (_Float16)lo.w;
            f[4] = (_Float16)hi.x; f[5] = (_Float16)hi.y;
            f[6] = (_Float16)hi.z; f[7] = (_Float16)hi.w;
            a[s] = f;
        }
        floatx4 acc[4];
#pragma unroll
        for (int nt = 0; nt < 4; ++nt)
            acc[nt] = (floatx4){bv[nt], bv[nt], bv[nt], bv[nt]};
#pragma unroll
        for (int s = 0; s < 4; ++s)
#pragma unroll
            for (int nt = 0; nt < 4; ++nt)
                acc[nt] = __builtin_amdgcn_mfma_f32_16x16x32_f16(
                              a[s], wf[nt][s], acc[nt], 0, 0, 0);
        // C layout: col n = lane&15, row m = quad*4 + r
#pragma unroll
        for (int nt = 0; nt < 4; ++nt) {
            const int n = 64 * wv + 16 * nt + l15;
#pragma unroll
            for (int r = 0; r < 4; ++r) {
                const size_t orow = r0 + 16 * rt + 4 * quad + r;
                out[orow * U + n] = acc[nt][r];
            }
        }
    }
}

// ---------------- Phase 2: the recurrence ----------------
__global__ __launch_bounds__(512, 2)
void rnn_mfma_kernel(const float* __restrict__ h0, const float* __restrict__ W,
                     float* __restrict__ out)
{
    __shared__ __align__(16) unsigned char lds[2 * BUF];

    const int tid  = threadIdx.x;
    const int lane = tid & 63;
    const int wv   = tid >> 6;     // wave 0..7, owns units [32wv, 32wv+32)
    const int l15  = lane & 15;
    const int quad = lane >> 4;
    const int b0   = blockIdx.x * 16;

    // ---- Wh fragments (B operand), pre-scaled by TANH_K ----
    half8 wf[2][NSL];
#pragma unroll
    for (int nt = 0; nt < 2; ++nt) {
        const int n = 32 * wv + 16 * nt + l15;
#pragma unroll
        for (int s = 0; s < NSL; ++s) {
            half8 f;
#pragma unroll
            for (int j = 0; j < 8; ++j) {
                const int k = 32 * s + 8 * quad + j;
                f[j] = (_Float16)(W[(size_t)k * U + n] * TANH_K);
            }
            wf[nt][s] = f;
        }
    }

    // ---- stage h0 (slices 0..7) into buffer 0 ----
    {
        const int hm = tid >> 5;          // batch row 0..15
        const int cc = tid & 31;          // unit chunk 0..31
        const float* hp = h0 + (size_t)(b0 + hm) * U + 8 * cc;
        cvt_write8(lds + (cc >> 2) * SS + (cc & 3) * QS + hm * 16,
                   *reinterpret_cast<const float4*>(hp),
                   *reinterpret_cast<const float4*>(hp + 4));
    }

    // hoisted per-output constants: i = 4*nt + r -> n = 32wv+16nt+l15,
    // m = 4quad+r.  optr[i] is BOTH the xp-load and the h-store address
    // (offset by t*U).
    float* optr[8];
    int    pubo[8];
#pragma unroll
    for (int i = 0; i < 8; ++i) {
        const int nt = i >> 2, r = i & 3;
        const int n = 32 * wv + 16 * nt + l15;
        const int m = 4 * quad + r;
        optr[i] = out + (size_t)(b0 + m) * T * U + n;
        pubo[i] = (n >> 5) * SS + ((n >> 3) & 3) * QS + m * 16 + (n & 7) * 2;
    }

    // prime the xp pipeline: xa = xp[0], xb = xp[1]
    float xa[8], xb[8];
#pragma unroll
    for (int i = 0; i < 8; ++i) xa[i] = optr[i][0];
#pragma unroll
    for (int i = 0; i < 8; ++i) xb[i] = optr[i][U];

    __syncthreads();

    const int aoff = quad * QS + l15 * 16;

    // One step. CO/NO: literal byte offsets of h-panel buffers t%2/(t+1)%2.
    // XR holds xp[t] on entry; refilled with xp[t+2] (consumed 2 steps on;
    // the intervening __syncthreads drains vmcnt(0), so it always arrives).
#define STEP(tt, CO, NO, XR)                                                   \
    do {                                                                       \
        const int t_ = (tt);                                                   \
        floatx4 acc[2];                                                        \
        acc[0] = (floatx4){XR[0], XR[1], XR[2], XR[3]};                        \
        acc[1] = (floatx4){XR[4], XR[5], XR[6], XR[7]};                        \
        const int tp_ = (t_ + 2 < T) ? (t_ + 2) : (T - 1);                     \
        _Pragma("unroll")                                                      \
        for (int i = 0; i < 8; ++i)                                            \
            XR[i] = optr[i][(size_t)tp_ * U];                                  \
        const unsigned char* ab = lds + (CO) + aoff;                           \
        half8 ah[NSL];                                                         \
        _Pragma("unroll")                                                      \
        for (int s = 0; s < NSL; ++s)                                          \
            ah[s] = *reinterpret_cast<const half8*>(ab + s * SS);              \
        __builtin_amdgcn_s_setprio(1);                                         \
        _Pragma("unroll")                                                      \
        for (int s = 0; s < NSL; ++s)                                          \
            _Pragma("unroll")                                                  \
            for (int nt = 0; nt < 2; ++nt)                                     \
                acc[nt] = __builtin_amdgcn_mfma_f32_16x16x32_f16(              \
                              ah[s], wf[nt][s], acc[nt], 0, 0, 0);             \
        __builtin_amdgcn_s_setprio(0);                                         \
        float hv[8];                                                           \
        _Pragma("unroll")                                                      \
        for (int i = 0; i < 8; ++i)                                            \
            hv[i] = tanh_prescaled(acc[i >> 2][i & 3]);                        \
        /* long-latency global stores first ... */                             \
        _Pragma("unroll")                                                      \
        for (int i = 0; i < 8; ++i)                                            \
            optr[i][(size_t)t_ * U] = hv[i];                                   \
        /* ... then LDS publish of h_{t+1} into buffer NO */                   \
        _Pragma("unroll")                                                      \
        for (int i = 0; i < 8; ++i)                                            \
            *reinterpret_cast<_Float16*>(lds + (NO) + pubo[i]) =               \
                (_Float16)hv[i];                                               \
        __syncthreads();                                                       \
    } while (0)

    for (int t = 0; t < T; t += 2) {
        STEP(t,     0,   BUF, xa);
        STEP(t + 1, BUF, 0,   xb);
    }
#undef STEP
}

extern "C" void kernel_launch(void* const* d_in, const int* in_sizes, int n_in,
                              void* d_out, int out_size, void* d_ws, size_t ws_size,
                              hipStream_t stream) {
    const float* x    = (const float*)d_in[0];
    const float* h0   = (const float*)d_in[1];
    const float* W    = (const float*)d_in[2];
    const float* bias = (const float*)d_in[3];
    float* out = (float*)d_out;

    // Phase 1: xp -> out (all CUs).  Phase 2 consumes it in-place.
    hipLaunchKernelGGL(xproj_kernel, dim3((B * T) / 64), dim3(256), 0, stream,
                       x, W, bias, out);
    hipLaunchKernelGGL(rnn_mfma_kernel, dim3(B / 16), dim3(512), 0, stream,
                       h0, W, out);
}